// Round 4
// baseline (1359.673 us; speedup 1.0000x reference)
//
#include <hip/hip_runtime.h>
#include <hip/hip_bf16.h>

// Problem constants (compile-time; n_heads input d_in[9] ignored).
// Inputs/outputs are FLOAT32 (per reference). Intermediates bf16 in d_ws.
#define BB      4
#define SEQ     4096
#define DMODEL  1024
#define NHEAD   16
#define DK      64
#define LK      256
#define BH      (BB*NHEAD)   // 64

typedef unsigned short u16;
typedef unsigned int   u32;

__device__ __forceinline__ float bf2f(u16 x) { return __uint_as_float(((u32)x) << 16); }
__device__ __forceinline__ u16 f2bf(float f) {
    u32 u = __float_as_uint(f);
    u32 r = u + 0x7fffu + ((u >> 16) & 1u);   // round-nearest-even
    return (u16)(r >> 16);
}
// unpack 8 bf16 (uint4) -> 8 floats
__device__ __forceinline__ void unpack8(uint4 r, float* f) {
    f[0] = __uint_as_float(r.x << 16); f[1] = __uint_as_float(r.x & 0xffff0000u);
    f[2] = __uint_as_float(r.y << 16); f[3] = __uint_as_float(r.y & 0xffff0000u);
    f[4] = __uint_as_float(r.z << 16); f[5] = __uint_as_float(r.z & 0xffff0000u);
    f[6] = __uint_as_float(r.w << 16); f[7] = __uint_as_float(r.w & 0xffff0000u);
}
__device__ __forceinline__ u32 packbf(float a, float b) {
    return (u32)f2bf(a) | ((u32)f2bf(b) << 16);
}

// ---------------------------------------------------------------------------
// Kernel 1: projections.  Out[bh][k][d] = sum_n W[n,k] * Inp[b,n,h*64+d] + bias[k]
// z=0: K/We/be -> KpT   z=1: V/Wf/bf -> Vp   (identical layouts [bh][LK][DK], bf16)
// grid (4 k-quarters, 64 bh, 2), block 256. micro-tile 4k x 4d per thread.
// ---------------------------------------------------------------------------
__global__ __launch_bounds__(256) void proj_kernel(
    const float* __restrict__ Kin, const float* __restrict__ Vin,
    const float* __restrict__ We,  const float* __restrict__ be,
    const float* __restrict__ Wf,  const float* __restrict__ bfp,
    u16* __restrict__ KpT, u16* __restrict__ Vp)
{
    const int kq = blockIdx.x;            // k0 = kq*64
    const int bh = blockIdx.y;
    const int b  = bh >> 4, h = bh & 15;
    const int isV = blockIdx.z;
    const float* Inp  = isV ? Vin : Kin;
    const float* W    = isV ? Wf  : We;
    const float* bias = isV ? bfp : be;
    u16* Out          = isV ? Vp  : KpT;

    __shared__ float Wl[64][68];          // [nn][k_local], pad 4 keeps 16B align
    __shared__ float Il[64][68];          // [nn][d]

    const int t  = threadIdx.x;
    const int k0 = kq * 64;
    const int kg = t >> 4;                // 0..15 -> k_local = kg*4
    const int dg = t & 15;                // 0..15 -> d = dg*4

    float acc[4][4];
#pragma unroll
    for (int i = 0; i < 4; ++i)
#pragma unroll
        for (int j = 0; j < 4; ++j) acc[i][j] = 0.f;

    for (int n0 = 0; n0 < SEQ; n0 += 64) {
        __syncthreads();
#pragma unroll
        for (int pass = 0; pass < 2; ++pass) {
            int idx = t + pass * 256;          // 0..511
            int nn  = idx >> 3;
            int c8  = (idx & 7) * 8;
            const float* wsrc = W + (size_t)(n0 + nn) * LK + k0 + c8;
            float4 w0 = *(const float4*)(wsrc);
            float4 w1 = *(const float4*)(wsrc + 4);
            *(float4*)&Wl[nn][c8]     = w0;
            *(float4*)&Wl[nn][c8 + 4] = w1;
            const float* isrc = Inp + ((size_t)b * SEQ + n0 + nn) * DMODEL + h * DK + c8;
            float4 i0 = *(const float4*)(isrc);
            float4 i1 = *(const float4*)(isrc + 4);
            *(float4*)&Il[nn][c8]     = i0;
            *(float4*)&Il[nn][c8 + 4] = i1;
        }
        __syncthreads();
#pragma unroll 8
        for (int nn = 0; nn < 64; ++nn) {
            const float4 w4 = *(const float4*)&Wl[nn][kg * 4];   // broadcast-ish
            const float4 i4 = *(const float4*)&Il[nn][dg * 4];   // 2-way, free
            acc[0][0] += w4.x * i4.x; acc[0][1] += w4.x * i4.y; acc[0][2] += w4.x * i4.z; acc[0][3] += w4.x * i4.w;
            acc[1][0] += w4.y * i4.x; acc[1][1] += w4.y * i4.y; acc[1][2] += w4.y * i4.z; acc[1][3] += w4.y * i4.w;
            acc[2][0] += w4.z * i4.x; acc[2][1] += w4.z * i4.y; acc[2][2] += w4.z * i4.z; acc[2][3] += w4.z * i4.w;
            acc[3][0] += w4.w * i4.x; acc[3][1] += w4.w * i4.y; acc[3][2] += w4.w * i4.z; acc[3][3] += w4.w * i4.w;
        }
    }

#pragma unroll
    for (int i = 0; i < 4; ++i) {
        int k = k0 + kg * 4 + i;
        float bv = bias[k];
        float a0 = acc[i][0] + bv, a1 = acc[i][1] + bv, a2 = acc[i][2] + bv, a3 = acc[i][3] + bv;
        uint2 o = make_uint2(packbf(a0, a1), packbf(a2, a3));
        *(uint2*)(Out + ((size_t)bh * LK + k) * DK + dg * 4) = o;
    }
}

// ---------------------------------------------------------------------------
// Kernel 2: fused scores + softmax + PV.  32 Q-rows per block, one (b,h) each.
// thread t: r = t&31 (row), g = t>>5 (k-group of 32 / d-group of 8).
// Kp/Vp (bf16) read from global (L2-resident, 4MB total). P round-trips LDS.
// ---------------------------------------------------------------------------
__global__ __launch_bounds__(256) void attn_kernel(
    const float* __restrict__ Qin, const u16* __restrict__ KpT,
    const u16* __restrict__ Vp,    u16* __restrict__ AO)
{
    const int bh = blockIdx.y, b = bh >> 4, h = bh & 15;
    const int n0 = blockIdx.x * 32;
    const int t  = threadIdx.x;
    const int r  = t & 31;
    const int g  = t >> 5;                  // 0..7

    __shared__ float ql[32][68];            // Q tile fp32, pad for b128 reads
    __shared__ u16   pl[32][LK + 2];        // P tile bf16
    __shared__ float red[8][33];            // softmax cross-group reduce

    // stage Q tile (rows n0..n0+31, cols h*64..h*64+63)
    {
        int rr = t >> 3, c8 = (t & 7) * 8;
        const float* qsrc = Qin + ((size_t)b * SEQ + n0 + rr) * DMODEL + h * DK + c8;
        float4 q0 = *(const float4*)(qsrc);
        float4 q1 = *(const float4*)(qsrc + 4);
        *(float4*)&ql[rr][c8]     = q0;
        *(float4*)&ql[rr][c8 + 4] = q1;
    }
    __syncthreads();

    // load this thread's q row into registers (reused by 32 k's)
    float qv[64];
#pragma unroll
    for (int dq = 0; dq < 16; ++dq) {
        float4 q4 = *(const float4*)&ql[r][dq * 4];
        qv[dq * 4 + 0] = q4.x; qv[dq * 4 + 1] = q4.y; qv[dq * 4 + 2] = q4.z; qv[dq * 4 + 3] = q4.w;
    }

    // phase 1: s[kk] = (q . Kp[bh][g*32+kk][:]) / 8
    float s[32];
    const u16* kbase = KpT + ((size_t)bh * LK + (size_t)g * 32) * DK;
#pragma unroll 2
    for (int kk = 0; kk < 32; ++kk) {
        const u16* krow = kbase + (size_t)kk * DK;
        float sum = 0.f;
#pragma unroll
        for (int dq = 0; dq < 8; ++dq) {
            uint4 kraw = *(const uint4*)(krow + dq * 8);
            float kf[8]; unpack8(kraw, kf);
            sum += qv[dq * 8 + 0] * kf[0] + qv[dq * 8 + 1] * kf[1]
                 + qv[dq * 8 + 2] * kf[2] + qv[dq * 8 + 3] * kf[3]
                 + qv[dq * 8 + 4] * kf[4] + qv[dq * 8 + 5] * kf[5]
                 + qv[dq * 8 + 6] * kf[6] + qv[dq * 8 + 7] * kf[7];
        }
        s[kk] = sum * 0.125f;
    }

    // softmax over 256 (8 groups x 32)
    float m = s[0];
#pragma unroll
    for (int kk = 1; kk < 32; ++kk) m = fmaxf(m, s[kk]);
    red[g][r] = m;
    __syncthreads();
    float mm = red[0][r];
#pragma unroll
    for (int gg = 1; gg < 8; ++gg) mm = fmaxf(mm, red[gg][r]);
    float l = 0.f;
#pragma unroll
    for (int kk = 0; kk < 32; ++kk) { s[kk] = __expf(s[kk] - mm); l += s[kk]; }
    __syncthreads();
    red[g][r] = l;
    __syncthreads();
    float ll = red[0][r];
#pragma unroll
    for (int gg = 1; gg < 8; ++gg) ll += red[gg][r];
    float inv = 1.0f / ll;
#pragma unroll
    for (int kk = 0; kk < 32; ++kk) pl[r][g * 32 + kk] = f2bf(s[kk] * inv);
    __syncthreads();

    // phase 2: out[r][d0..d0+7] = sum_k P[r][k] * Vp[bh][k][d]
    const int d0 = g * 8;
    float acc[8];
#pragma unroll
    for (int i = 0; i < 8; ++i) acc[i] = 0.f;
    const u16* vbase = Vp + (size_t)bh * LK * DK + d0;
#pragma unroll 4
    for (int k = 0; k < LK; ++k) {
        float p = bf2f(pl[r][k]);
        uint4 vraw = *(const uint4*)(vbase + (size_t)k * DK);
        float vf[8]; unpack8(vraw, vf);
#pragma unroll
        for (int i = 0; i < 8; ++i) acc[i] += p * vf[i];
    }
    uint4 o;
    o.x = packbf(acc[0], acc[1]); o.y = packbf(acc[2], acc[3]);
    o.z = packbf(acc[4], acc[5]); o.w = packbf(acc[6], acc[7]);
    *(uint4*)(AO + ((size_t)b * SEQ + n0 + r) * DMODEL + h * DK + d0) = o;
}

// ---------------------------------------------------------------------------
// Kernel 3: Out[16384][1024] = AO(bf16) @ Wo(f32) + bo. 128x128 tile, 8x8 micro.
// ---------------------------------------------------------------------------
__global__ __launch_bounds__(256) void out_gemm(
    const u16* __restrict__ AO, const float* __restrict__ Wo,
    const float* __restrict__ bo, float* __restrict__ Out)
{
    const int c0 = blockIdx.x * 128;
    const int r0 = blockIdx.y * 128;
    const int t  = threadIdx.x;
    const int tx = t & 15, ty = t >> 4;

    __shared__ float Al[16][132];   // [k_local][row]
    __shared__ float Bl[16][132];   // [k_local][col]

    float acc[8][8];
#pragma unroll
    for (int i = 0; i < 8; ++i)
#pragma unroll
        for (int j = 0; j < 8; ++j) acc[i][j] = 0.f;

    for (int k0 = 0; k0 < DMODEL; k0 += 16) {
        __syncthreads();
        {
            // A tile: 128 rows x 16 k (bf16 source)
            int row = t >> 1, kc = (t & 1) * 8;
            uint4 araw = *(const uint4*)(AO + (size_t)(r0 + row) * DMODEL + k0 + kc);
            float af[8]; unpack8(araw, af);
#pragma unroll
            for (int j = 0; j < 8; ++j) Al[kc + j][row] = af[j];
            // B tile: 16 k x 128 cols (f32 source)
            int kk = t >> 4, c8 = (t & 15) * 8;
            const float* bsrc = Wo + (size_t)(k0 + kk) * DMODEL + c0 + c8;
            float4 b0 = *(const float4*)(bsrc);
            float4 b1 = *(const float4*)(bsrc + 4);
            *(float4*)&Bl[kk][c8]     = b0;
            *(float4*)&Bl[kk][c8 + 4] = b1;
        }
        __syncthreads();
#pragma unroll 8
        for (int kk = 0; kk < 16; ++kk) {
            float4 a0 = *(const float4*)&Al[kk][ty * 8];
            float4 a1 = *(const float4*)&Al[kk][ty * 8 + 4];
            float4 b0 = *(const float4*)&Bl[kk][tx * 8];
            float4 b1 = *(const float4*)&Bl[kk][tx * 8 + 4];
            float a[8] = {a0.x, a0.y, a0.z, a0.w, a1.x, a1.y, a1.z, a1.w};
            float bb[8] = {b0.x, b0.y, b0.z, b0.w, b1.x, b1.y, b1.z, b1.w};
#pragma unroll
            for (int i = 0; i < 8; ++i)
#pragma unroll
                for (int j = 0; j < 8; ++j) acc[i][j] += a[i] * bb[j];
        }
    }

    float bv[8];
#pragma unroll
    for (int j = 0; j < 8; ++j) bv[j] = bo[c0 + tx * 8 + j];
#pragma unroll
    for (int i = 0; i < 8; ++i) {
        int row = r0 + ty * 8 + i;
        float* dst = Out + (size_t)row * DMODEL + c0 + tx * 8;
        float4 o0 = make_float4(acc[i][0] + bv[0], acc[i][1] + bv[1],
                                acc[i][2] + bv[2], acc[i][3] + bv[3]);
        float4 o1 = make_float4(acc[i][4] + bv[4], acc[i][5] + bv[5],
                                acc[i][6] + bv[6], acc[i][7] + bv[7]);
        *(float4*)(dst)     = o0;
        *(float4*)(dst + 4) = o1;
    }
}

// ---------------------------------------------------------------------------
extern "C" void kernel_launch(void* const* d_in, const int* in_sizes, int n_in,
                              void* d_out, int out_size, void* d_ws, size_t ws_size,
                              hipStream_t stream)
{
    const float* K   = (const float*)d_in[0];
    const float* Q   = (const float*)d_in[1];
    const float* V   = (const float*)d_in[2];
    const float* We  = (const float*)d_in[3];
    const float* be  = (const float*)d_in[4];
    const float* Wf  = (const float*)d_in[5];
    const float* bfp = (const float*)d_in[6];
    const float* Wo  = (const float*)d_in[7];
    const float* bo  = (const float*)d_in[8];
    float* Out = (float*)d_out;

    // workspace (bf16 intermediates): KpT (2MB) | Vp (2MB) | AO (33.5MB)
    u16* KpT = (u16*)d_ws;
    u16* Vp  = KpT + (size_t)BH * LK * DK;
    u16* AO  = Vp  + (size_t)BH * LK * DK;

    proj_kernel<<<dim3(4, 64, 2), 256, 0, stream>>>(K, V, We, be, Wf, bfp, KpT, Vp);
    attn_kernel<<<dim3(SEQ / 32, BH), 256, 0, stream>>>(Q, KpT, Vp, AO);
    out_gemm<<<dim3(DMODEL / 128, (BB * SEQ) / 128), 256, 0, stream>>>(AO, Wo, bo, Out);
}

// Round 5
// 915.332 us; speedup vs baseline: 1.4854x; 1.4854x over previous
//
#include <hip/hip_runtime.h>
#include <hip/hip_bf16.h>

// Problem constants (compile-time; n_heads input d_in[9] ignored).
// Inputs/outputs FLOAT32 (per reference). Intermediates bf16 in d_ws.
// R5: attention converted to MFMA (16x16x32 bf16). Vp now stored TRANSPOSED
//     [bh][DK][LK] so PV B-fragments are contiguous in the k (lk) dim.
#define BB      4
#define SEQ     4096
#define DMODEL  1024
#define NHEAD   16
#define DK      64
#define LK      256
#define BH      (BB*NHEAD)   // 64

typedef unsigned short u16;
typedef unsigned int   u32;
typedef float f32x4  __attribute__((ext_vector_type(4)));
typedef short bf16x8 __attribute__((ext_vector_type(8)));

__device__ __forceinline__ float bf2f(u16 x) { return __uint_as_float(((u32)x) << 16); }
__device__ __forceinline__ u16 f2bf(float f) {
    u32 u = __float_as_uint(f);
    u32 r = u + 0x7fffu + ((u >> 16) & 1u);   // round-nearest-even
    return (u16)(r >> 16);
}
// unpack 8 bf16 (uint4) -> 8 floats
__device__ __forceinline__ void unpack8(uint4 r, float* f) {
    f[0] = __uint_as_float(r.x << 16); f[1] = __uint_as_float(r.x & 0xffff0000u);
    f[2] = __uint_as_float(r.y << 16); f[3] = __uint_as_float(r.y & 0xffff0000u);
    f[4] = __uint_as_float(r.z << 16); f[5] = __uint_as_float(r.z & 0xffff0000u);
    f[6] = __uint_as_float(r.w << 16); f[7] = __uint_as_float(r.w & 0xffff0000u);
}
__device__ __forceinline__ u32 packbf(float a, float b) {
    return (u32)f2bf(a) | ((u32)f2bf(b) << 16);
}

// ---------------------------------------------------------------------------
// Kernel 1: projections.
// z=0: KpT[bh][LK][DK] = sum_n We[n,k]*K[b,n,h*64+d] + be[k]   (d contiguous)
// z=1: VpT[bh][DK][LK] = sum_n Wf[n,k]*V[b,n,h*64+d] + bf[k]   (k contiguous!)
// ---------------------------------------------------------------------------
__global__ __launch_bounds__(256) void proj_kernel(
    const float* __restrict__ Kin, const float* __restrict__ Vin,
    const float* __restrict__ We,  const float* __restrict__ be,
    const float* __restrict__ Wf,  const float* __restrict__ bfp,
    u16* __restrict__ KpT, u16* __restrict__ VpT)
{
    const int kq = blockIdx.x;            // k0 = kq*64
    const int bh = blockIdx.y;
    const int b  = bh >> 4, h = bh & 15;
    const int isV = blockIdx.z;
    const float* Inp  = isV ? Vin : Kin;
    const float* W    = isV ? Wf  : We;
    const float* bias = isV ? bfp : be;
    u16* Out          = isV ? VpT : KpT;

    __shared__ float Wl[64][68];          // [nn][k_local]
    __shared__ float Il[64][68];          // [nn][d]

    const int t  = threadIdx.x;
    const int k0 = kq * 64;
    const int kg = t >> 4;                // k_local = kg*4
    const int dg = t & 15;                // d = dg*4

    float acc[4][4];
#pragma unroll
    for (int i = 0; i < 4; ++i)
#pragma unroll
        for (int j = 0; j < 4; ++j) acc[i][j] = 0.f;

    for (int n0 = 0; n0 < SEQ; n0 += 64) {
        __syncthreads();
#pragma unroll
        for (int pass = 0; pass < 2; ++pass) {
            int idx = t + pass * 256;
            int nn  = idx >> 3;
            int c8  = (idx & 7) * 8;
            const float* wsrc = W + (size_t)(n0 + nn) * LK + k0 + c8;
            *(float4*)&Wl[nn][c8]     = *(const float4*)(wsrc);
            *(float4*)&Wl[nn][c8 + 4] = *(const float4*)(wsrc + 4);
            const float* isrc = Inp + ((size_t)b * SEQ + n0 + nn) * DMODEL + h * DK + c8;
            *(float4*)&Il[nn][c8]     = *(const float4*)(isrc);
            *(float4*)&Il[nn][c8 + 4] = *(const float4*)(isrc + 4);
        }
        __syncthreads();
#pragma unroll 8
        for (int nn = 0; nn < 64; ++nn) {
            const float4 w4 = *(const float4*)&Wl[nn][kg * 4];
            const float4 i4 = *(const float4*)&Il[nn][dg * 4];
            acc[0][0] += w4.x * i4.x; acc[0][1] += w4.x * i4.y; acc[0][2] += w4.x * i4.z; acc[0][3] += w4.x * i4.w;
            acc[1][0] += w4.y * i4.x; acc[1][1] += w4.y * i4.y; acc[1][2] += w4.y * i4.z; acc[1][3] += w4.y * i4.w;
            acc[2][0] += w4.z * i4.x; acc[2][1] += w4.z * i4.y; acc[2][2] += w4.z * i4.z; acc[2][3] += w4.z * i4.w;
            acc[3][0] += w4.w * i4.x; acc[3][1] += w4.w * i4.y; acc[3][2] += w4.w * i4.z; acc[3][3] += w4.w * i4.w;
        }
    }

    if (!isV) {
        // KpT[bh][k][d]: pack 4 d for each of 4 k
#pragma unroll
        for (int i = 0; i < 4; ++i) {
            int k = k0 + kg * 4 + i;
            float bv = bias[k];
            uint2 o = make_uint2(packbf(acc[i][0] + bv, acc[i][1] + bv),
                                 packbf(acc[i][2] + bv, acc[i][3] + bv));
            *(uint2*)(Out + ((size_t)bh * LK + k) * DK + dg * 4) = o;
        }
    } else {
        // VpT[bh][d][k]: pack 4 consecutive k for each of 4 d (bias varies with k)
        float bv0 = bias[k0 + kg * 4 + 0], bv1 = bias[k0 + kg * 4 + 1];
        float bv2 = bias[k0 + kg * 4 + 2], bv3 = bias[k0 + kg * 4 + 3];
#pragma unroll
        for (int j = 0; j < 4; ++j) {
            int d = dg * 4 + j;
            uint2 o = make_uint2(packbf(acc[0][j] + bv0, acc[1][j] + bv1),
                                 packbf(acc[2][j] + bv2, acc[3][j] + bv3));
            *(uint2*)(Out + ((size_t)bh * DK + d) * LK + k0 + kg * 4) = o;
        }
    }
}

// ---------------------------------------------------------------------------
// Kernel 2 (MFMA): fused scores+softmax+PV. Block = 64 Q-rows x one (b,h),
// 4 waves, wave w owns rows w*16..w*16+15 end-to-end (no cross-wave deps).
// A layout: A[m=lane&15][k=quad*8+j]; B: B[k=quad*8+j][n=lane&15];
// C/D: col=lane&15, row=quad*4+reg  (learn_hip m89/m91/m120 verified).
// ---------------------------------------------------------------------------
__global__ __launch_bounds__(256) void attn_mfma(
    const float* __restrict__ Qin, const u16* __restrict__ KpT,
    const u16* __restrict__ VpT,   u16* __restrict__ AO)
{
    const int bh = blockIdx.y, b = bh >> 4, h = bh & 15;
    const int n0 = blockIdx.x * 64;
    const int t  = threadIdx.x;
    const int w    = t >> 6;          // wave 0..3
    const int lane = t & 63;
    const int q    = lane >> 4;       // quad 0..3
    const int c    = lane & 15;

    __shared__ u16 Qs[64][72];        // Q tile bf16 (+8 pad: 144B stride, 2-way free)
    __shared__ u16 Pl[64][264];       // P tile bf16 (+8 pad: 528B stride, 16B aligned)

    // ---- stage Q (fp32 -> bf16), wave w stages its own 16 rows ----
    {
        int lr = lane >> 2, col0 = (lane & 3) * 16;
        const float* src = Qin + ((size_t)b * SEQ + n0 + w * 16 + lr) * DMODEL + h * DK + col0;
        float4 f0 = ((const float4*)src)[0];
        float4 f1 = ((const float4*)src)[1];
        float4 f2 = ((const float4*)src)[2];
        float4 f3 = ((const float4*)src)[3];
        uint4 p0, p1;
        p0.x = packbf(f0.x, f0.y); p0.y = packbf(f0.z, f0.w);
        p0.z = packbf(f1.x, f1.y); p0.w = packbf(f1.z, f1.w);
        p1.x = packbf(f2.x, f2.y); p1.y = packbf(f2.z, f2.w);
        p1.z = packbf(f3.x, f3.y); p1.w = packbf(f3.z, f3.w);
        *(uint4*)&Qs[w * 16 + lr][col0]     = p0;
        *(uint4*)&Qs[w * 16 + lr][col0 + 8] = p1;
    }
    __syncthreads();   // cheap paranoia; all deps are wave-local

    // ---- A-fragments for QK^T (row m = w*16 + c, k = d) ----
    bf16x8 a0 = *(const bf16x8*)&Qs[w * 16 + c][q * 8];
    bf16x8 a1 = *(const bf16x8*)&Qs[w * 16 + c][32 + q * 8];

    // ---- scores: 16 col-tiles of 16 lk each; B-frags straight from L2 ----
    f32x4 sc[16];
#pragma unroll
    for (int nt = 0; nt < 16; ++nt) sc[nt] = (f32x4){0.f, 0.f, 0.f, 0.f};

    const u16* kb = KpT + (size_t)bh * LK * DK;
#pragma unroll
    for (int nt = 0; nt < 16; ++nt) {
        const u16* kp = kb + (size_t)(nt * 16 + c) * DK + q * 8;
        bf16x8 b0 = *(const bf16x8*)(kp);
        bf16x8 b1 = *(const bf16x8*)(kp + 32);
        sc[nt] = __builtin_amdgcn_mfma_f32_16x16x32_bf16(a0, b0, sc[nt], 0, 0, 0);
        sc[nt] = __builtin_amdgcn_mfma_f32_16x16x32_bf16(a1, b1, sc[nt], 0, 0, 0);
    }

    // ---- softmax over 256 cols, entirely in registers ----
    // lane holds rows (q*4+reg), cols (nt*16 + c). Reduce: 16 in-lane + 4 shuffles.
    float mx[4] = {-1e30f, -1e30f, -1e30f, -1e30f};
#pragma unroll
    for (int nt = 0; nt < 16; ++nt) {
        sc[nt] *= 0.125f;   // 1/sqrt(DK)
#pragma unroll
        for (int r = 0; r < 4; ++r) mx[r] = fmaxf(mx[r], sc[nt][r]);
    }
#pragma unroll
    for (int d = 1; d < 16; d <<= 1)
#pragma unroll
        for (int r = 0; r < 4; ++r) mx[r] = fmaxf(mx[r], __shfl_xor(mx[r], d, 64));

    float sm[4] = {0.f, 0.f, 0.f, 0.f};
#pragma unroll
    for (int nt = 0; nt < 16; ++nt)
#pragma unroll
        for (int r = 0; r < 4; ++r) {
            float e = __expf(sc[nt][r] - mx[r]);
            sc[nt][r] = e;
            sm[r] += e;
        }
#pragma unroll
    for (int d = 1; d < 16; d <<= 1)
#pragma unroll
        for (int r = 0; r < 4; ++r) sm[r] += __shfl_xor(sm[r], d, 64);
    float inv[4];
#pragma unroll
    for (int r = 0; r < 4; ++r) inv[r] = 1.0f / sm[r];

    // ---- P: C-layout regs -> LDS (row-major) for A-operand re-read ----
#pragma unroll
    for (int nt = 0; nt < 16; ++nt)
#pragma unroll
        for (int r = 0; r < 4; ++r)
            Pl[w * 16 + q * 4 + r][nt * 16 + c] = f2bf(sc[nt][r] * inv[r]);

    // ---- PV: out[16 x 64] per wave; A from LDS, B from VpT (L2) ----
    f32x4 ov[4];
#pragma unroll
    for (int nt = 0; nt < 4; ++nt) ov[nt] = (f32x4){0.f, 0.f, 0.f, 0.f};
    const u16* vb = VpT + (size_t)bh * DK * LK;
#pragma unroll
    for (int ks = 0; ks < 8; ++ks) {
        bf16x8 pa = *(const bf16x8*)&Pl[w * 16 + c][ks * 32 + q * 8];
#pragma unroll
        for (int nt = 0; nt < 4; ++nt) {
            bf16x8 vf = *(const bf16x8*)(vb + (size_t)(nt * 16 + c) * LK + ks * 32 + q * 8);
            ov[nt] = __builtin_amdgcn_mfma_f32_16x16x32_bf16(pa, vf, ov[nt], 0, 0, 0);
        }
    }

    // ---- stage out tile into reused Qs, then coalesced 16B stores ----
#pragma unroll
    for (int nt = 0; nt < 4; ++nt)
#pragma unroll
        for (int r = 0; r < 4; ++r)
            Qs[w * 16 + q * 4 + r][nt * 16 + c] = f2bf(ov[nt][r]);

#pragma unroll
    for (int pass = 0; pass < 2; ++pass) {
        int lr  = w * 16 + pass * 8 + (lane >> 3);
        int col = (lane & 7) * 8;
        uint4 vv = *(uint4*)&Qs[lr][col];
        *(uint4*)(AO + ((size_t)b * SEQ + n0 + lr) * DMODEL + h * DK + col) = vv;
    }
}

// ---------------------------------------------------------------------------
// Kernel 3: Out[16384][1024] = AO(bf16) @ Wo(f32) + bo. 128x128 tile, 8x8 micro.
// (unchanged this round; MFMA conversion next)
// ---------------------------------------------------------------------------
__global__ __launch_bounds__(256) void out_gemm(
    const u16* __restrict__ AO, const float* __restrict__ Wo,
    const float* __restrict__ bo, float* __restrict__ Out)
{
    const int c0 = blockIdx.x * 128;
    const int r0 = blockIdx.y * 128;
    const int t  = threadIdx.x;
    const int tx = t & 15, ty = t >> 4;

    __shared__ float Al[16][132];   // [k_local][row]
    __shared__ float Bl[16][132];   // [k_local][col]

    float acc[8][8];
#pragma unroll
    for (int i = 0; i < 8; ++i)
#pragma unroll
        for (int j = 0; j < 8; ++j) acc[i][j] = 0.f;

    for (int k0 = 0; k0 < DMODEL; k0 += 16) {
        __syncthreads();
        {
            int row = t >> 1, kc = (t & 1) * 8;
            uint4 araw = *(const uint4*)(AO + (size_t)(r0 + row) * DMODEL + k0 + kc);
            float af[8]; unpack8(araw, af);
#pragma unroll
            for (int j = 0; j < 8; ++j) Al[kc + j][row] = af[j];
            int kk = t >> 4, c8 = (t & 15) * 8;
            const float* bsrc = Wo + (size_t)(k0 + kk) * DMODEL + c0 + c8;
            *(float4*)&Bl[kk][c8]     = *(const float4*)(bsrc);
            *(float4*)&Bl[kk][c8 + 4] = *(const float4*)(bsrc + 4);
        }
        __syncthreads();
#pragma unroll 8
        for (int kk = 0; kk < 16; ++kk) {
            float4 a0 = *(const float4*)&Al[kk][ty * 8];
            float4 a1 = *(const float4*)&Al[kk][ty * 8 + 4];
            float4 b0 = *(const float4*)&Bl[kk][tx * 8];
            float4 b1 = *(const float4*)&Bl[kk][tx * 8 + 4];
            float a[8] = {a0.x, a0.y, a0.z, a0.w, a1.x, a1.y, a1.z, a1.w};
            float bb[8] = {b0.x, b0.y, b0.z, b0.w, b1.x, b1.y, b1.z, b1.w};
#pragma unroll
            for (int i = 0; i < 8; ++i)
#pragma unroll
                for (int j = 0; j < 8; ++j) acc[i][j] += a[i] * bb[j];
        }
    }

    float bv[8];
#pragma unroll
    for (int j = 0; j < 8; ++j) bv[j] = bo[c0 + tx * 8 + j];
#pragma unroll
    for (int i = 0; i < 8; ++i) {
        int row = r0 + ty * 8 + i;
        float* dst = Out + (size_t)row * DMODEL + c0 + tx * 8;
        *(float4*)(dst)     = make_float4(acc[i][0] + bv[0], acc[i][1] + bv[1],
                                          acc[i][2] + bv[2], acc[i][3] + bv[3]);
        *(float4*)(dst + 4) = make_float4(acc[i][4] + bv[4], acc[i][5] + bv[5],
                                          acc[i][6] + bv[6], acc[i][7] + bv[7]);
    }
}

// ---------------------------------------------------------------------------
extern "C" void kernel_launch(void* const* d_in, const int* in_sizes, int n_in,
                              void* d_out, int out_size, void* d_ws, size_t ws_size,
                              hipStream_t stream)
{
    const float* K   = (const float*)d_in[0];
    const float* Q   = (const float*)d_in[1];
    const float* V   = (const float*)d_in[2];
    const float* We  = (const float*)d_in[3];
    const float* be  = (const float*)d_in[4];
    const float* Wf  = (const float*)d_in[5];
    const float* bfp = (const float*)d_in[6];
    const float* Wo  = (const float*)d_in[7];
    const float* bo  = (const float*)d_in[8];
    float* Out = (float*)d_out;

    // workspace (bf16): KpT [bh][LK][DK] 2MB | VpT [bh][DK][LK] 2MB | AO 33.5MB
    u16* KpT = (u16*)d_ws;
    u16* VpT = KpT + (size_t)BH * LK * DK;
    u16* AO  = VpT + (size_t)BH * LK * DK;

    proj_kernel<<<dim3(4, 64, 2), 256, 0, stream>>>(K, V, We, be, Wf, bfp, KpT, VpT);
    attn_mfma<<<dim3(SEQ / 64, BH), 256, 0, stream>>>(Q, KpT, VpT, AO);
    out_gemm<<<dim3(DMODEL / 128, (BB * SEQ) / 128), 256, 0, stream>>>(AO, Wo, bo, Out);
}